// Round 15
// baseline (55.645 us; speedup 1.0000x reference)
//
#include <hip/hip_runtime.h>
#include <hip/hip_bf16.h>

// out[8192,64] = L[8192,8192] (fp32) @ M[8192,64] (fp32)
// R15 = R13 (champion, 54.6us) + per-block k-step ROTATION (rot = rb & 15):
// de-correlates HBM channel-select address bits across blocks (all blocks no
// longer read the same 256B column phase simultaneously). Step order is
// irrelevant to the accumulation; ledger/buffers/LDS/occupancy unchanged.
// K1 (build_btf): zero d_out slice + BTF = B bf16 in MFMA-fragment order.
// K2 (crowd_mm): BM=128, 512 thr (8 waves), LDS 80KB (2 blocks/CU):
//     A fp32 via global_load_lds(16B) XOR-swizzled dbuf 2x32KB;
//     B fragment-ordered 1KB gl_lds per wave/step dbuf 2x8KB;
//     counted s_waitcnt vmcnt(5); two barriers per 64-k step.
//     Split-K=8, fp32 atomic epilogue.

#define NPED 8192
#define HID  64
#define BM   128
#define BK   64
#define KSPLIT 8
#define KRANGE (NPED / KSPLIT)   // 1024
#define NSTEPS (KRANGE / BK)     // 16

typedef __bf16 bf16x8 __attribute__((ext_vector_type(8)));
typedef float  f32x4  __attribute__((ext_vector_type(4)));
typedef unsigned short u16;
typedef u16 u16x8 __attribute__((ext_vector_type(8)));

__device__ __forceinline__ u16 bfc(float f) {
    __bf16 b = (__bf16)f;
    return __builtin_bit_cast(u16, b);
}

__device__ __forceinline__ void gl_lds16(const void* g, void* l) {
    __builtin_amdgcn_global_load_lds(
        (const __attribute__((address_space(1))) void*)g,
        (__attribute__((address_space(3))) void*)l, 16, 0, 0);
}

// ---- K1: zero d_out + B [8192,64] fp32 -> BTF fragment-ordered bf16 (1 MB) ----
// BTF[((S*8+f)*64 + l)*8 + j] = bf16(B[S*64 + (f>>2)*32 + (l>>4)*8 + j][(f&3)*16 + (l&15)])
__global__ __launch_bounds__(256)
void build_btf(const float* __restrict__ B, u16* __restrict__ BTF,
               float4* __restrict__ outz) {
    __shared__ u16 t[64][72];
    const int tid = threadIdx.x;
    const int S   = blockIdx.x;          // 0..127
    const int kb  = S * 64;
    {   // zero this block's slice of d_out (131072 float4 / 128 blocks)
        const float4 z = {0.f, 0.f, 0.f, 0.f};
        #pragma unroll
        for (int i = 0; i < 4; ++i) outz[S * 1024 + i * 256 + tid] = z;
    }
    {
        const int r  = tid >> 2;
        const int c0 = (tid & 3) * 16;
        const float* p = B + (long)(kb + r) * HID + c0;
        #pragma unroll
        for (int j = 0; j < 16; j += 4) {
            float4 v = *(const float4*)(p + j);
            t[c0 + j + 0][r] = bfc(v.x);
            t[c0 + j + 1][r] = bfc(v.y);
            t[c0 + j + 2][r] = bfc(v.z);
            t[c0 + j + 3][r] = bfc(v.w);
        }
    }
    __syncthreads();
    {
        const int f  = tid >> 5;
        const int s  = f >> 2, tt = f & 3;
        const int l0 = (tid & 31) * 2;
        u16* q = BTF + ((long)(S * 8 + f) * 64 + l0) * 8;
        #pragma unroll
        for (int i = 0; i < 2; ++i) {
            const int l  = l0 + i;
            const int h  = tt * 16 + (l & 15);
            const int kl = s * 32 + (l >> 4) * 8;
            u16x8 v;
            #pragma unroll
            for (int j = 0; j < 8; ++j) v[j] = t[h][kl + j];
            *(u16x8*)(q + i * 8) = v;
        }
    }
}

// ---- K2: R13 streaming MFMA + per-block k-step rotation ----
__global__ __launch_bounds__(512, 4)
void crowd_mm(const float* __restrict__ A, const u16* __restrict__ BTF,
              float* __restrict__ out)
{
    __shared__ float Aa[BM * BK];   // 32 KB
    __shared__ float Ab[BM * BK];   // 32 KB
    __shared__ u16   Ba[4096];      // 8 KB
    __shared__ u16   Bb[4096];      // 8 KB

    const int tid  = threadIdx.x;
    const int lane = tid & 63;
    const int w    = tid >> 6;       // wave 0..7, owns rows w*16..+15
    const int rb   = blockIdx.x;     // 0..63
    const int ks   = blockIdx.y;     // 0..7
    const int rot  = rb & 15;        // per-block k-step phase rotation

    const int l15  = lane & 15;
    const int l4   = lane >> 4;
    const int cb16 = l15 * 16;

    const char* Abase = (const char*)(A + (long)(rb * BM) * NPED + (long)ks * KRANGE);
    const u16*  Bbase = BTF + ((long)(ks * NSTEPS) * 8 + w) * 512 + lane * 8;

    f32x4 acc[4] = {};

    // rotated step: consumption order rot, rot+1, ..., wrapping mod 16
#define RS(X) (((X) + rot) & 15)

    // per wave per step: 1 B-stage + 4 A-stage global_load_lds (5 vmem)
#define STAGE(ALDS, BLDS, STEP) do {                                             \
    const int st_ = (STEP);                                                      \
    gl_lds16(Bbase + (long)st_ * (8 * 512), (char*)(BLDS) + w * 1024);           \
    _Pragma("unroll")                                                            \
    for (int I = 0; I < 4; ++I) {                                                \
        const int row4 = w * 16 + I * 4 + l4;                                    \
        const char* src = Abase + (long)row4 * (NPED * 4)                        \
                        + (long)st_ * 256 + (cb16 ^ ((row4 & 7) << 4));          \
        gl_lds16(src, (char*)(ALDS) + (w * 4 + I) * 1024);                       \
    }                                                                            \
} while (0)

#define HALF(ALDS, BLDS, VM) do {                                                \
    asm volatile("s_waitcnt vmcnt(" #VM ")" ::: "memory");                       \
    __builtin_amdgcn_s_barrier();                                                \
    const char* ab_ = (const char*)(ALDS);                                       \
    const char* bb_ = (const char*)(BLDS);                                       \
    const int row_ = w * 16 + l15;                                               \
    const int sw_  = (row_ & 7) << 4;                                            \
    const int rB_  = row_ * 256;                                                 \
    float4 fa0 = *(const float4*)(ab_ + rB_ + ((l4 * 32)            ^ sw_));     \
    float4 fa1 = *(const float4*)(ab_ + rB_ + ((l4 * 32 + 16)       ^ sw_));     \
    float4 fa2 = *(const float4*)(ab_ + rB_ + ((128 + l4 * 32)      ^ sw_));     \
    float4 fa3 = *(const float4*)(ab_ + rB_ + ((128 + l4 * 32 + 16) ^ sw_));     \
    bf16x8 bf0 = *(const bf16x8*)(bb_ + 0 * 1024 + lane * 16);                   \
    bf16x8 bf1 = *(const bf16x8*)(bb_ + 1 * 1024 + lane * 16);                   \
    bf16x8 bf2 = *(const bf16x8*)(bb_ + 2 * 1024 + lane * 16);                   \
    bf16x8 bf3 = *(const bf16x8*)(bb_ + 3 * 1024 + lane * 16);                   \
    bf16x8 bf4 = *(const bf16x8*)(bb_ + 4 * 1024 + lane * 16);                   \
    bf16x8 bf5 = *(const bf16x8*)(bb_ + 5 * 1024 + lane * 16);                   \
    bf16x8 bf6 = *(const bf16x8*)(bb_ + 6 * 1024 + lane * 16);                   \
    bf16x8 bf7 = *(const bf16x8*)(bb_ + 7 * 1024 + lane * 16);                   \
    asm volatile("s_waitcnt lgkmcnt(0)" ::: "memory");                           \
    __builtin_amdgcn_s_barrier();                                                \
    bf16x8 af0, af1;                                                             \
    af0[0] = (__bf16)fa0.x; af0[1] = (__bf16)fa0.y;                              \
    af0[2] = (__bf16)fa0.z; af0[3] = (__bf16)fa0.w;                              \
    af0[4] = (__bf16)fa1.x; af0[5] = (__bf16)fa1.y;                              \
    af0[6] = (__bf16)fa1.z; af0[7] = (__bf16)fa1.w;                              \
    af1[0] = (__bf16)fa2.x; af1[1] = (__bf16)fa2.y;                              \
    af1[2] = (__bf16)fa2.z; af1[3] = (__bf16)fa2.w;                              \
    af1[4] = (__bf16)fa3.x; af1[5] = (__bf16)fa3.y;                              \
    af1[6] = (__bf16)fa3.z; af1[7] = (__bf16)fa3.w;                              \
    acc[0] = __builtin_amdgcn_mfma_f32_16x16x32_bf16(af0, bf0, acc[0], 0, 0, 0); \
    acc[1] = __builtin_amdgcn_mfma_f32_16x16x32_bf16(af0, bf1, acc[1], 0, 0, 0); \
    acc[2] = __builtin_amdgcn_mfma_f32_16x16x32_bf16(af0, bf2, acc[2], 0, 0, 0); \
    acc[3] = __builtin_amdgcn_mfma_f32_16x16x32_bf16(af0, bf3, acc[3], 0, 0, 0); \
    acc[0] = __builtin_amdgcn_mfma_f32_16x16x32_bf16(af1, bf4, acc[0], 0, 0, 0); \
    acc[1] = __builtin_amdgcn_mfma_f32_16x16x32_bf16(af1, bf5, acc[1], 0, 0, 0); \
    acc[2] = __builtin_amdgcn_mfma_f32_16x16x32_bf16(af1, bf6, acc[2], 0, 0, 0); \
    acc[3] = __builtin_amdgcn_mfma_f32_16x16x32_bf16(af1, bf7, acc[3], 0, 0, 0); \
} while (0)

    // Prologue: two steps in flight (10 vmem outstanding per wave)
    STAGE(Aa, Ba, RS(0));
    STAGE(Ab, Bb, RS(1));

    #pragma unroll
    for (int it = 0; it < 7; ++it) {
        HALF(Aa, Ba, 5);               // consume logical step 2*it
        STAGE(Aa, Ba, RS(2 * it + 2));
        HALF(Ab, Bb, 5);               // consume logical step 2*it+1
        STAGE(Ab, Bb, RS(2 * it + 3));
    }
    HALF(Aa, Ba, 5);                   // step 14 (step-15 loads stay in flight)
    HALF(Ab, Bb, 0);                   // step 15 (final drain)

    // Epilogue: C/D layout col = lane&15, row = (lane>>4)*4 + reg
    #pragma unroll
    for (int t = 0; t < 4; ++t) {
        #pragma unroll
        for (int r = 0; r < 4; ++r) {
            int row = rb * BM + w * 16 + l4 * 4 + r;
            int col = t * 16 + l15;
            atomicAdd(&out[row * HID + col], acc[t][r]);
        }
    }
#undef RS
#undef STAGE
#undef HALF
}

extern "C" void kernel_launch(void* const* d_in, const int* in_sizes, int n_in,
                              void* d_out, int out_size, void* d_ws, size_t ws_size,
                              hipStream_t stream) {
    const float* A = (const float*)d_in[0];   // location_data [8192, 8192]
    const float* B = (const float*)d_in[1];   // motion_data   [8192, 64]
    float* out = (float*)d_out;               // [8192, 64]
    u16* BTF = (u16*)d_ws;                    // 1 MB fragment-ordered B

    build_btf<<<dim3(NPED / 64), 256, 0, stream>>>(B, BTF, (float4*)d_out);

    dim3 grid(NPED / BM, KSPLIT);
    crowd_mm<<<grid, 512, 0, stream>>>(A, BTF, out);
}

// Round 16
// 54.303 us; speedup vs baseline: 1.0247x; 1.0247x over previous
//
#include <hip/hip_runtime.h>
#include <hip/hip_bf16.h>

// out[8192,64] = L[8192,8192] (fp32) @ M[8192,64] (fp32)
// FINAL (= R13 champion, 54.6us): R6 main loop + memset folded into build_btf.
// K1 (build_btf): zero d_out slice + BTF = B bf16 in MFMA-fragment order.
// K2 (crowd_mm): BM=128, 512 thr (8 waves), LDS 80KB (2 blocks/CU):
//     A fp32 via global_load_lds(16B) XOR-swizzled dbuf 2x32KB;
//     B fragment-ordered 1KB gl_lds per wave/step dbuf 2x8KB;
//     counted s_waitcnt vmcnt(5); two barriers per 64-k step.
//     Split-K=8, fp32 atomic epilogue (measured cheaper than partials+reduce).
// Lever ledger (measured): sync restructure x3, grain-up x2, epilogue-replace,
// paired-issue, channel-rotation all null/negative; memset-fold +3us (kept).

#define NPED 8192
#define HID  64
#define BM   128
#define BK   64
#define KSPLIT 8
#define KRANGE (NPED / KSPLIT)   // 1024
#define NSTEPS (KRANGE / BK)     // 16

typedef __bf16 bf16x8 __attribute__((ext_vector_type(8)));
typedef float  f32x4  __attribute__((ext_vector_type(4)));
typedef unsigned short u16;
typedef u16 u16x8 __attribute__((ext_vector_type(8)));

__device__ __forceinline__ u16 bfc(float f) {
    __bf16 b = (__bf16)f;
    return __builtin_bit_cast(u16, b);
}

__device__ __forceinline__ void gl_lds16(const void* g, void* l) {
    __builtin_amdgcn_global_load_lds(
        (const __attribute__((address_space(1))) void*)g,
        (__attribute__((address_space(3))) void*)l, 16, 0, 0);
}

// ---- K1: zero d_out + B [8192,64] fp32 -> BTF fragment-ordered bf16 (1 MB) ----
// BTF[((S*8+f)*64 + l)*8 + j] = bf16(B[S*64 + (f>>2)*32 + (l>>4)*8 + j][(f&3)*16 + (l&15)])
__global__ __launch_bounds__(256)
void build_btf(const float* __restrict__ B, u16* __restrict__ BTF,
               float4* __restrict__ outz) {
    __shared__ u16 t[64][72];
    const int tid = threadIdx.x;
    const int S   = blockIdx.x;          // 0..127
    const int kb  = S * 64;
    {   // zero this block's slice of d_out (131072 float4 / 128 blocks)
        const float4 z = {0.f, 0.f, 0.f, 0.f};
        #pragma unroll
        for (int i = 0; i < 4; ++i) outz[S * 1024 + i * 256 + tid] = z;
    }
    {
        const int r  = tid >> 2;
        const int c0 = (tid & 3) * 16;
        const float* p = B + (long)(kb + r) * HID + c0;
        #pragma unroll
        for (int j = 0; j < 16; j += 4) {
            float4 v = *(const float4*)(p + j);
            t[c0 + j + 0][r] = bfc(v.x);
            t[c0 + j + 1][r] = bfc(v.y);
            t[c0 + j + 2][r] = bfc(v.z);
            t[c0 + j + 3][r] = bfc(v.w);
        }
    }
    __syncthreads();
    {
        const int f  = tid >> 5;
        const int s  = f >> 2, tt = f & 3;
        const int l0 = (tid & 31) * 2;
        u16* q = BTF + ((long)(S * 8 + f) * 64 + l0) * 8;
        #pragma unroll
        for (int i = 0; i < 2; ++i) {
            const int l  = l0 + i;
            const int h  = tt * 16 + (l & 15);
            const int kl = s * 32 + (l >> 4) * 8;
            u16x8 v;
            #pragma unroll
            for (int j = 0; j < 8; ++j) v[j] = t[h][kl + j];
            *(u16x8*)(q + i * 8) = v;
        }
    }
}

// ---- K2: streaming MFMA ----
__global__ __launch_bounds__(512, 4)
void crowd_mm(const float* __restrict__ A, const u16* __restrict__ BTF,
              float* __restrict__ out)
{
    __shared__ float Aa[BM * BK];   // 32 KB
    __shared__ float Ab[BM * BK];   // 32 KB
    __shared__ u16   Ba[4096];      // 8 KB
    __shared__ u16   Bb[4096];      // 8 KB

    const int tid  = threadIdx.x;
    const int lane = tid & 63;
    const int w    = tid >> 6;       // wave 0..7, owns rows w*16..+15
    const int rb   = blockIdx.x;     // 0..63
    const int ks   = blockIdx.y;     // 0..7

    const int l15  = lane & 15;
    const int l4   = lane >> 4;
    const int cb16 = l15 * 16;

    const char* Abase = (const char*)(A + (long)(rb * BM) * NPED + (long)ks * KRANGE);
    const u16*  Bbase = BTF + ((long)(ks * NSTEPS) * 8 + w) * 512 + lane * 8;

    f32x4 acc[4] = {};

    // per wave per step: 1 B-stage + 4 A-stage global_load_lds (5 vmem)
#define STAGE(ALDS, BLDS, STEP) do {                                             \
    gl_lds16(Bbase + (long)(STEP) * (8 * 512), (char*)(BLDS) + w * 1024);        \
    _Pragma("unroll")                                                            \
    for (int I = 0; I < 4; ++I) {                                                \
        const int row4 = w * 16 + I * 4 + l4;                                    \
        const char* src = Abase + (long)row4 * (NPED * 4)                        \
                        + (long)(STEP) * 256 + (cb16 ^ ((row4 & 7) << 4));       \
        gl_lds16(src, (char*)(ALDS) + (w * 4 + I) * 1024);                       \
    }                                                                            \
} while (0)

#define HALF(ALDS, BLDS, VM) do {                                                \
    asm volatile("s_waitcnt vmcnt(" #VM ")" ::: "memory");                       \
    __builtin_amdgcn_s_barrier();                                                \
    const char* ab_ = (const char*)(ALDS);                                       \
    const char* bb_ = (const char*)(BLDS);                                       \
    const int row_ = w * 16 + l15;                                               \
    const int sw_  = (row_ & 7) << 4;                                            \
    const int rB_  = row_ * 256;                                                 \
    float4 fa0 = *(const float4*)(ab_ + rB_ + ((l4 * 32)            ^ sw_));     \
    float4 fa1 = *(const float4*)(ab_ + rB_ + ((l4 * 32 + 16)       ^ sw_));     \
    float4 fa2 = *(const float4*)(ab_ + rB_ + ((128 + l4 * 32)      ^ sw_));     \
    float4 fa3 = *(const float4*)(ab_ + rB_ + ((128 + l4 * 32 + 16) ^ sw_));     \
    bf16x8 bf0 = *(const bf16x8*)(bb_ + 0 * 1024 + lane * 16);                   \
    bf16x8 bf1 = *(const bf16x8*)(bb_ + 1 * 1024 + lane * 16);                   \
    bf16x8 bf2 = *(const bf16x8*)(bb_ + 2 * 1024 + lane * 16);                   \
    bf16x8 bf3 = *(const bf16x8*)(bb_ + 3 * 1024 + lane * 16);                   \
    bf16x8 bf4 = *(const bf16x8*)(bb_ + 4 * 1024 + lane * 16);                   \
    bf16x8 bf5 = *(const bf16x8*)(bb_ + 5 * 1024 + lane * 16);                   \
    bf16x8 bf6 = *(const bf16x8*)(bb_ + 6 * 1024 + lane * 16);                   \
    bf16x8 bf7 = *(const bf16x8*)(bb_ + 7 * 1024 + lane * 16);                   \
    asm volatile("s_waitcnt lgkmcnt(0)" ::: "memory");                           \
    __builtin_amdgcn_s_barrier();                                                \
    bf16x8 af0, af1;                                                             \
    af0[0] = (__bf16)fa0.x; af0[1] = (__bf16)fa0.y;                              \
    af0[2] = (__bf16)fa0.z; af0[3] = (__bf16)fa0.w;                              \
    af0[4] = (__bf16)fa1.x; af0[5] = (__bf16)fa1.y;                              \
    af0[6] = (__bf16)fa1.z; af0[7] = (__bf16)fa1.w;                              \
    af1[0] = (__bf16)fa2.x; af1[1] = (__bf16)fa2.y;                              \
    af1[2] = (__bf16)fa2.z; af1[3] = (__bf16)fa2.w;                              \
    af1[4] = (__bf16)fa3.x; af1[5] = (__bf16)fa3.y;                              \
    af1[6] = (__bf16)fa3.z; af1[7] = (__bf16)fa3.w;                              \
    acc[0] = __builtin_amdgcn_mfma_f32_16x16x32_bf16(af0, bf0, acc[0], 0, 0, 0); \
    acc[1] = __builtin_amdgcn_mfma_f32_16x16x32_bf16(af0, bf1, acc[1], 0, 0, 0); \
    acc[2] = __builtin_amdgcn_mfma_f32_16x16x32_bf16(af0, bf2, acc[2], 0, 0, 0); \
    acc[3] = __builtin_amdgcn_mfma_f32_16x16x32_bf16(af0, bf3, acc[3], 0, 0, 0); \
    acc[0] = __builtin_amdgcn_mfma_f32_16x16x32_bf16(af1, bf4, acc[0], 0, 0, 0); \
    acc[1] = __builtin_amdgcn_mfma_f32_16x16x32_bf16(af1, bf5, acc[1], 0, 0, 0); \
    acc[2] = __builtin_amdgcn_mfma_f32_16x16x32_bf16(af1, bf6, acc[2], 0, 0, 0); \
    acc[3] = __builtin_amdgcn_mfma_f32_16x16x32_bf16(af1, bf7, acc[3], 0, 0, 0); \
} while (0)

    // Prologue: two steps in flight (10 vmem outstanding per wave)
    STAGE(Aa, Ba, 0);
    STAGE(Ab, Bb, 1);

    #pragma unroll
    for (int it = 0; it < 7; ++it) {
        HALF(Aa, Ba, 5);               // consume step 2*it
        STAGE(Aa, Ba, 2 * it + 2);
        HALF(Ab, Bb, 5);               // consume step 2*it+1
        STAGE(Ab, Bb, 2 * it + 3);
    }
    HALF(Aa, Ba, 5);                   // step 14 (step-15 loads stay in flight)
    HALF(Ab, Bb, 0);                   // step 15 (final drain)

    // Epilogue: C/D layout col = lane&15, row = (lane>>4)*4 + reg
    #pragma unroll
    for (int t = 0; t < 4; ++t) {
        #pragma unroll
        for (int r = 0; r < 4; ++r) {
            int row = rb * BM + w * 16 + l4 * 4 + r;
            int col = t * 16 + l15;
            atomicAdd(&out[row * HID + col], acc[t][r]);
        }
    }
#undef STAGE
#undef HALF
}

extern "C" void kernel_launch(void* const* d_in, const int* in_sizes, int n_in,
                              void* d_out, int out_size, void* d_ws, size_t ws_size,
                              hipStream_t stream) {
    const float* A = (const float*)d_in[0];   // location_data [8192, 8192]
    const float* B = (const float*)d_in[1];   // motion_data   [8192, 64]
    float* out = (float*)d_out;               // [8192, 64]
    u16* BTF = (u16*)d_ws;                    // 1 MB fragment-ordered B

    build_btf<<<dim3(NPED / 64), 256, 0, stream>>>(B, BTF, (float4*)d_out);

    dim3 grid(NPED / BM, KSPLIT);
    crowd_mm<<<grid, 512, 0, stream>>>(A, BTF, out);
}